// Round 3
// baseline (1018.677 us; speedup 1.0000x reference)
//
#include <hip/hip_runtime.h>
#include <math.h>

// ---------------------------------------------------------------------------
// GCN link predictor on MI355X, round 3.
// Changes vs round 2 (scatter was 138us with 100MB write-amplified traffic):
//   - CSR build: two-phase bucketed scatter (128 nodes/bucket). Phase A bins
//     edges at per-bucket atomic cursors (dense write fronts -> L2 merges
//     lines, ~6.5MB HBM write). Phase B: one block/bucket, LDS per-node
//     cursors, fine scatter into contiguous 16KB CSR segment.
//   - Scan: hierarchical (block sums -> 1-wave scan -> per-block scan),
//     fused with dinv. Replaces 49-chunk single-block scan.
// NOTE: phase A packs (col&127)<<16 | row into one int -> requires N<=65536.
// ---------------------------------------------------------------------------

typedef __attribute__((ext_vector_type(8))) short short8x;
typedef __attribute__((ext_vector_type(4))) float f32x4;

__device__ __forceinline__ unsigned short f2bf(float f) {
  unsigned int u = __float_as_uint(f);
  unsigned int r = u + 0x7FFFu + ((u >> 16) & 1u);  // RNE
  return (unsigned short)(r >> 16);
}
__device__ __forceinline__ float bf2f(unsigned short u) {
  return __uint_as_float(((unsigned int)u) << 16);
}

// ------------------------------ graph build --------------------------------

__global__ void zero_int_kernel(int* __restrict__ p, int n) {
  int i = blockIdx.x * blockDim.x + threadIdx.x;
  if (i < n) p[i] = 0;
}

__global__ void degree_hist_kernel(const int* __restrict__ col, int* __restrict__ deg, int E) {
  int i = blockIdx.x * blockDim.x + threadIdx.x;
  if (i < E) atomicAdd(&deg[col[i]], 1);
}

// 256 threads/block, 1024 elements/block: per-block sum of deg.
__global__ __launch_bounds__(256) void scan_blocksum_kernel(const int* __restrict__ deg,
                                                            int* __restrict__ bsum, int n) {
  __shared__ int ws[4];
  int base = blockIdx.x * 1024;
  int tid = threadIdx.x;
  int s = 0;
#pragma unroll
  for (int j = 0; j < 4; ++j) {
    int i = base + tid + j * 256;
    if (i < n) s += deg[i];
  }
#pragma unroll
  for (int d = 1; d < 64; d <<= 1) s += __shfl_xor(s, d, 64);
  if ((tid & 63) == 0) ws[tid >> 6] = s;
  __syncthreads();
  if (tid == 0) bsum[blockIdx.x] = ws[0] + ws[1] + ws[2] + ws[3];
}

// One wave: exclusive scan of nb (<=64) block sums in place; write total.
__global__ __launch_bounds__(64) void scan_bsum_kernel(int* __restrict__ bsum, int nb,
                                                       int* __restrict__ total) {
  int lane = threadIdx.x;
  int v = (lane < nb) ? bsum[lane] : 0;
  int incl = v;
#pragma unroll
  for (int d = 1; d < 64; d <<= 1) {
    int t = __shfl_up(incl, d, 64);
    if (lane >= d) incl += t;
  }
  if (lane < nb) bsum[lane] = incl - v;
  if (lane == 63) *total = incl;
}

// Per-block exclusive scan (1024 elems, 4/thread contiguous) + add block
// offset; writes offs and dinv.
__global__ __launch_bounds__(256) void scan_final_kernel(const int* __restrict__ deg,
                                                         const int* __restrict__ bsum,
                                                         int* __restrict__ offs,
                                                         float* __restrict__ dinv, int n) {
  __shared__ int wsum[4];
  int tid = threadIdx.x;
  int lane = tid & 63;
  int wid = tid >> 6;
  int idx0 = blockIdx.x * 1024 + tid * 4;
  int v[4];
#pragma unroll
  for (int j = 0; j < 4; ++j) {
    int i = idx0 + j;
    v[j] = (i < n) ? deg[i] : 0;
  }
  int tsum = v[0] + v[1] + v[2] + v[3];
  int incl = tsum;
#pragma unroll
  for (int d = 1; d < 64; d <<= 1) {
    int t = __shfl_up(incl, d, 64);
    if (lane >= d) incl += t;
  }
  if (lane == 63) wsum[wid] = incl;
  __syncthreads();
  int woff = 0;
#pragma unroll
  for (int w = 0; w < 4; ++w)
    if (w < wid) woff += wsum[w];
  int run = woff + incl - tsum + bsum[blockIdx.x];
#pragma unroll
  for (int j = 0; j < 4; ++j) {
    int i = idx0 + j;
    if (i < n) {
      offs[i] = run;
      dinv[i] = rsqrtf((float)v[j] + 1.0f);
      run += v[j];
    }
  }
}

// bcur[b] = offs[b*128]; also writes offs[N] = total edges.
__global__ void bucket_init_kernel(const int* __restrict__ offs, const int* __restrict__ total,
                                   int* __restrict__ bcur, int* __restrict__ offs_n, int NB) {
  int b = blockIdx.x * blockDim.x + threadIdx.x;
  if (b < NB) bcur[b] = offs[b * 128];
  if (b == 0) *offs_n = *total;
}

// Phase A: bin edges by col>>7 at per-bucket cursor. Packed payload
// (requires row < 65536): (col&127)<<16 | row.
__global__ void scatterA_kernel(const int* __restrict__ row, const int* __restrict__ col,
                                int* __restrict__ bcur, int* __restrict__ staging, int E) {
  int i = blockIdx.x * blockDim.x + threadIdx.x;
  if (i < E) {
    int c = col[i];
    int p = atomicAdd(&bcur[c >> 7], 1);
    staging[p] = (row[i] & 0xFFFF) | ((c & 127) << 16);
  }
}

// Phase B: one block per bucket; per-node LDS cursors; fine scatter into the
// bucket's contiguous CSR segment.
__global__ __launch_bounds__(256) void scatterB_kernel(const int* __restrict__ staging,
                                                       const int* __restrict__ offs,
                                                       int* __restrict__ csr_row, int N) {
  __shared__ int cur[128];
  int b = blockIdx.x;
  int n0 = b * 128;
  int nn = min(128, N - n0);
  int tid = threadIdx.x;
  if (tid < nn) cur[tid] = offs[n0 + tid];
  __syncthreads();
  int s = offs[n0];
  int e = offs[min(n0 + 128, N)];
  for (int t = s + tid; t < e; t += 256) {
    int v = staging[t];
    int p = atomicAdd(&cur[v >> 16], 1);
    csr_row[p] = v & 0xFFFF;
  }
}

// --------------------- weight prep: fragment ordering ----------------------
__global__ void prep_bfrag_kernel(const float* __restrict__ W, unsigned short* __restrict__ out,
                                  int K, int N) {
  int idx = blockIdx.x * blockDim.x + threadIdx.x;
  int KS = K / 32;
  int total = (N / 16) * KS * 64;
  if (idx >= total) return;
  int lane = idx & 63;
  int t = idx >> 6;
  int ks = t % KS;
  int nt = t / KS;
  int n = nt * 16 + (lane & 15);
  int k0 = ks * 32 + (lane >> 4) * 8;
  unsigned short* o = out + (size_t)idx * 8;
#pragma unroll
  for (int j = 0; j < 8; ++j) o[j] = f2bf(W[(size_t)(k0 + j) * N + n]);
}

// ------------------------------- MFMA GEMM ---------------------------------
template <int K, int N, bool ABF16>
__global__ __launch_bounds__(256) void mfma_gemm_kernel(const void* __restrict__ Ap,
                                                        const unsigned short* __restrict__ Bfrag,
                                                        unsigned short* __restrict__ Cout, int M) {
  constexpr int KS = K / 32;
  constexpr int NT = N / 16;
  const int lane = threadIdx.x & 63;
  const int wid = threadIdx.x >> 6;
  const int quad = lane >> 4;
  const int lc = lane & 15;
  const int mbase = blockIdx.x * 128 + wid * 32;
  if (mbase >= M) return;

  f32x4 acc[2][NT];
#pragma unroll
  for (int mt = 0; mt < 2; ++mt)
#pragma unroll
    for (int nt = 0; nt < NT; ++nt) acc[mt][nt] = (f32x4){0.f, 0.f, 0.f, 0.f};

  int r0 = mbase + lc;
  int r1 = mbase + 16 + lc;
  if (r0 >= M) r0 = M - 1;
  if (r1 >= M) r1 = M - 1;

#pragma unroll
  for (int ks = 0; ks < KS; ++ks) {
    const int k0 = ks * 32 + quad * 8;
    short8x a[2];
    if constexpr (ABF16) {
      const unsigned short* A = (const unsigned short*)Ap;
      a[0] = *(const short8x*)(A + (size_t)r0 * K + k0);
      a[1] = *(const short8x*)(A + (size_t)r1 * K + k0);
    } else {
      const float* A = (const float*)Ap;
      const float4* p0 = (const float4*)(A + (size_t)r0 * K + k0);
      const float4* p1 = (const float4*)(A + (size_t)r1 * K + k0);
      float4 u0 = p0[0], v0 = p0[1];
      float4 u1 = p1[0], v1 = p1[1];
      short8x t0, t1;
      t0[0] = (short)f2bf(u0.x); t0[1] = (short)f2bf(u0.y);
      t0[2] = (short)f2bf(u0.z); t0[3] = (short)f2bf(u0.w);
      t0[4] = (short)f2bf(v0.x); t0[5] = (short)f2bf(v0.y);
      t0[6] = (short)f2bf(v0.z); t0[7] = (short)f2bf(v0.w);
      t1[0] = (short)f2bf(u1.x); t1[1] = (short)f2bf(u1.y);
      t1[2] = (short)f2bf(u1.z); t1[3] = (short)f2bf(u1.w);
      t1[4] = (short)f2bf(v1.x); t1[5] = (short)f2bf(v1.y);
      t1[6] = (short)f2bf(v1.z); t1[7] = (short)f2bf(v1.w);
      a[0] = t0;
      a[1] = t1;
    }
#pragma unroll
    for (int nt = 0; nt < NT; ++nt) {
      short8x b = *(const short8x*)(Bfrag + (((size_t)nt * KS + ks) * 64 + lane) * 8);
      acc[0][nt] = __builtin_amdgcn_mfma_f32_16x16x32_bf16(a[0], b, acc[0][nt], 0, 0, 0);
      acc[1][nt] = __builtin_amdgcn_mfma_f32_16x16x32_bf16(a[1], b, acc[1][nt], 0, 0, 0);
    }
  }

#pragma unroll
  for (int mt = 0; mt < 2; ++mt)
#pragma unroll
    for (int nt = 0; nt < NT; ++nt)
#pragma unroll
      for (int reg = 0; reg < 4; ++reg) {
        int row = mbase + mt * 16 + quad * 4 + reg;
        if (row < M) Cout[(size_t)row * N + nt * 16 + lc] = f2bf(acc[mt][nt][reg]);
      }
}

// --------------------------- aggregation (bf16) ----------------------------
template <int F>
__global__ void agg_bn_relu_kernel(const unsigned short* __restrict__ xw,
                                   const int* __restrict__ offs, const int* __restrict__ rows,
                                   const float* __restrict__ dinv, const float* __restrict__ bias,
                                   const float* __restrict__ gamma, const float* __restrict__ beta,
                                   const float* __restrict__ mean, const float* __restrict__ var,
                                   unsigned short* __restrict__ out) {
  const int i = blockIdx.x;
  const int f = threadIdx.x;
  const float di = dinv[i];
  const int s = offs[i], e = offs[i + 1];
  float acc = 0.f;
  int t = s;
  for (; t + 4 <= e; t += 4) {
    int r0 = rows[t], r1 = rows[t + 1], r2 = rows[t + 2], r3 = rows[t + 3];
    float w0 = dinv[r0], w1 = dinv[r1], w2 = dinv[r2], w3 = dinv[r3];
    acc += w0 * bf2f(xw[(size_t)r0 * F + f]) + w1 * bf2f(xw[(size_t)r1 * F + f]) +
           w2 * bf2f(xw[(size_t)r2 * F + f]) + w3 * bf2f(xw[(size_t)r3 * F + f]);
  }
  for (; t < e; ++t) {
    int r = rows[t];
    acc += dinv[r] * bf2f(xw[(size_t)r * F + f]);
  }
  float v = di * acc + di * di * bf2f(xw[(size_t)i * F + f]) + bias[f];
  v = (v - mean[f]) * rsqrtf(var[f] + 1e-5f) * gamma[f] + beta[f];
  out[(size_t)i * F + f] = f2bf(fmaxf(v, 0.f));
}

// ------------------------------- edge head ---------------------------------
__global__ __launch_bounds__(256) void head_mfma_kernel(
    const unsigned short* __restrict__ z, const int* __restrict__ src,
    const int* __restrict__ dst, const unsigned short* __restrict__ bfragH,
    const float* __restrict__ hb1, const float* __restrict__ hw2,
    const float* __restrict__ hb2, float* __restrict__ out, int P) {
  const int lane = threadIdx.x & 63;
  const int quad = lane >> 4;
  const int lc = lane & 15;

  short8x bf[4][4];
#pragma unroll
  for (int nt = 0; nt < 4; ++nt)
#pragma unroll
    for (int ks = 0; ks < 4; ++ks)
      bf[nt][ks] = *(const short8x*)(bfragH + (((size_t)nt * 4 + ks) * 64 + lane) * 8);

  float b1v[4], w2v[4];
#pragma unroll
  for (int nt = 0; nt < 4; ++nt) {
    b1v[nt] = hb1[nt * 16 + lc];
    w2v[nt] = hw2[nt * 16 + lc];
  }
  const float bias2 = hb2[0];

  const int nchunks = (P + 15) / 16;
  const int gw = blockIdx.x * 4 + (threadIdx.x >> 6);
  const int nw = gridDim.x * 4;

  for (int ch = gw; ch < nchunks; ch += nw) {
    int p = ch * 16 + lc;
    int pc = p < P ? p : P - 1;
    int s = src[pc], d = dst[pc];
    const unsigned short* zs = z + (size_t)s * 64;
    const unsigned short* zd = z + (size_t)d * 64;
    short8x a[4];
    a[0] = *(const short8x*)(zs + quad * 8);
    a[1] = *(const short8x*)(zs + 32 + quad * 8);
    a[2] = *(const short8x*)(zd + quad * 8);
    a[3] = *(const short8x*)(zd + 32 + quad * 8);

    f32x4 acc[4];
#pragma unroll
    for (int nt = 0; nt < 4; ++nt) acc[nt] = (f32x4){0.f, 0.f, 0.f, 0.f};
#pragma unroll
    for (int nt = 0; nt < 4; ++nt)
#pragma unroll
      for (int t = 0; t < 4; ++t)
        acc[nt] = __builtin_amdgcn_mfma_f32_16x16x32_bf16(a[t], bf[nt][t], acc[nt], 0, 0, 0);

    float part[4];
#pragma unroll
    for (int reg = 0; reg < 4; ++reg) {
      float sum = 0.f;
#pragma unroll
      for (int nt = 0; nt < 4; ++nt) sum += fmaxf(acc[nt][reg] + b1v[nt], 0.f) * w2v[nt];
      part[reg] = sum;
    }
#pragma unroll
    for (int m = 1; m < 16; m <<= 1) {
#pragma unroll
      for (int reg = 0; reg < 4; ++reg) part[reg] += __shfl_xor(part[reg], m, 64);
    }
    if (lc == 0) {
      int pbase = ch * 16 + quad * 4;
      float4 o;
      o.x = 1.0f / (1.0f + __expf(-(part[0] + bias2)));
      o.y = 1.0f / (1.0f + __expf(-(part[1] + bias2)));
      o.z = 1.0f / (1.0f + __expf(-(part[2] + bias2)));
      o.w = 1.0f / (1.0f + __expf(-(part[3] + bias2)));
      if (pbase + 3 < P) {
        *(float4*)(out + pbase) = o;
      } else {
        float ov[4] = {o.x, o.y, o.z, o.w};
        for (int reg = 0; reg < 4; ++reg)
          if (pbase + reg < P) out[pbase + reg] = ov[reg];
      }
    }
  }
}

// ------------------------------- launcher ----------------------------------

extern "C" void kernel_launch(void* const* d_in, const int* in_sizes, int n_in,
                              void* d_out, int out_size, void* d_ws, size_t ws_size,
                              hipStream_t stream) {
  const float* x = (const float*)d_in[0];
  const int* ei = (const int*)d_in[1];
  const int* src = (const int*)d_in[2];
  const int* dst = (const int*)d_in[3];
  const float* W1 = (const float*)d_in[4];
  const float* b1 = (const float*)d_in[5];
  const float* g1 = (const float*)d_in[6];
  const float* be1 = (const float*)d_in[7];
  const float* mu1 = (const float*)d_in[8];
  const float* va1 = (const float*)d_in[9];
  const float* W2 = (const float*)d_in[10];
  const float* b2 = (const float*)d_in[11];
  const float* g2 = (const float*)d_in[12];
  const float* be2 = (const float*)d_in[13];
  const float* mu2 = (const float*)d_in[14];
  const float* va2 = (const float*)d_in[15];
  const float* hW1 = (const float*)d_in[16];
  const float* hb1 = (const float*)d_in[17];
  const float* hW2 = (const float*)d_in[18];
  const float* hb2 = (const float*)d_in[19];
  float* out = (float*)d_out;

  const int N = in_sizes[0] / 512;
  const int E = in_sizes[1] / 2;
  const int P = in_sizes[2];
  const int* row = ei;
  const int* col = ei + E;
  const int NB = (N + 127) / 128;       // scatter buckets
  const int NSB = (N + 1023) / 1024;    // scan blocks

  char* wp = (char*)d_ws;
  auto alloc = [&](size_t bytes) {
    char* p = wp;
    wp += (bytes + 255) & ~(size_t)255;
    return p;
  };
  unsigned short* xw1 = (unsigned short*)alloc((size_t)N * 128 * 2);
  unsigned short* h = (unsigned short*)alloc((size_t)N * 128 * 2);
  unsigned short* xw2 = (unsigned short*)alloc((size_t)N * 64 * 2);
  unsigned short* z = (unsigned short*)alloc((size_t)N * 64 * 2);
  float* dinv = (float*)alloc((size_t)N * 4);
  int* deg = (int*)alloc((size_t)N * 4);
  int* offs = (int*)alloc((size_t)(N + 1) * 4);
  int* csr_row = (int*)alloc((size_t)E * 4);
  int* staging = (int*)alloc((size_t)E * 4);
  int* bsum = (int*)alloc((size_t)NSB * 4);
  int* bcur = (int*)alloc((size_t)NB * 4);
  int* total = (int*)alloc(256);
  unsigned short* bfW1 = (unsigned short*)alloc(512 * 128 * 2);
  unsigned short* bfW2 = (unsigned short*)alloc(128 * 64 * 2);
  unsigned short* bfH = (unsigned short*)alloc(128 * 64 * 2);
  (void)ws_size;
  (void)n_in;
  (void)out_size;

  // --- graph structure ---
  hipLaunchKernelGGL(zero_int_kernel, dim3((N + 255) / 256), dim3(256), 0, stream, deg, N);
  hipLaunchKernelGGL(degree_hist_kernel, dim3((E + 255) / 256), dim3(256), 0, stream, col, deg, E);
  hipLaunchKernelGGL(scan_blocksum_kernel, dim3(NSB), dim3(256), 0, stream, deg, bsum, N);
  hipLaunchKernelGGL(scan_bsum_kernel, dim3(1), dim3(64), 0, stream, bsum, NSB, total);
  hipLaunchKernelGGL(scan_final_kernel, dim3(NSB), dim3(256), 0, stream, deg, bsum, offs, dinv, N);
  hipLaunchKernelGGL(bucket_init_kernel, dim3((NB + 255) / 256), dim3(256), 0, stream, offs, total,
                     bcur, offs + N, NB);
  hipLaunchKernelGGL(scatterA_kernel, dim3((E + 255) / 256), dim3(256), 0, stream, row, col, bcur,
                     staging, E);
  hipLaunchKernelGGL(scatterB_kernel, dim3(NB), dim3(256), 0, stream, staging, offs, csr_row, N);

  // --- weight fragment prep ---
  hipLaunchKernelGGL(prep_bfrag_kernel, dim3((8 * 16 * 64 + 255) / 256), dim3(256), 0, stream, W1,
                     bfW1, 512, 128);
  hipLaunchKernelGGL(prep_bfrag_kernel, dim3((4 * 4 * 64 + 255) / 256), dim3(256), 0, stream, W2,
                     bfW2, 128, 64);
  hipLaunchKernelGGL(prep_bfrag_kernel, dim3((4 * 4 * 64 + 255) / 256), dim3(256), 0, stream, hW1,
                     bfH, 128, 64);

  // --- layer 1 ---
  hipLaunchKernelGGL((mfma_gemm_kernel<512, 128, false>), dim3((N + 127) / 128), dim3(256), 0,
                     stream, x, bfW1, xw1, N);
  hipLaunchKernelGGL((agg_bn_relu_kernel<128>), dim3(N), dim3(128), 0, stream, xw1, offs, csr_row,
                     dinv, b1, g1, be1, mu1, va1, h);

  // --- layer 2 ---
  hipLaunchKernelGGL((mfma_gemm_kernel<128, 64, true>), dim3((N + 127) / 128), dim3(256), 0, stream,
                     h, bfW2, xw2, N);
  hipLaunchKernelGGL((agg_bn_relu_kernel<64>), dim3(N), dim3(64), 0, stream, xw2, offs, csr_row,
                     dinv, b2, g2, be2, mu2, va2, z);

  // --- edge head ---
  hipLaunchKernelGGL(head_mfma_kernel, dim3(2048), dim3(256), 0, stream, z, src, dst, bfH, hb1,
                     hW2, hb2, out, P);
}

// Round 4
// 467.875 us; speedup vs baseline: 2.1772x; 2.1772x over previous
//
#include <hip/hip_runtime.h>
#include <math.h>

// ---------------------------------------------------------------------------
// GCN link predictor on MI355X, round 4.
// CSR build redesigned after round-3 regression (391-counter global atomic
// contention = 557us):
//   binA: per-block LDS histogram over 196 buckets (256 nodes each), ONE
//         global atomicAdd per (block,bucket) to reserve a contiguous range,
//         scatter via LDS cursors -> per-block contiguous runs (~21 edges)
//         so L2 merges lines. Global atomics: 77k total, ~391/counter.
//   binB: one block per bucket, per-node LDS cursors, dense 32KB segment;
//         CSR entry = bf16(dinv[row])<<16 | row  (kills the 2x1.6M random
//         dinv gathers in the agg layers).
// ---------------------------------------------------------------------------

typedef __attribute__((ext_vector_type(8))) short short8x;
typedef __attribute__((ext_vector_type(4))) float f32x4;

__device__ __forceinline__ unsigned short f2bf(float f) {
  unsigned int u = __float_as_uint(f);
  unsigned int r = u + 0x7FFFu + ((u >> 16) & 1u);  // RNE
  return (unsigned short)(r >> 16);
}
__device__ __forceinline__ float bf2f(unsigned short u) {
  return __uint_as_float(((unsigned int)u) << 16);
}

// ------------------------------ graph build --------------------------------

__global__ void zero_int_kernel(int* __restrict__ p, int n) {
  int i = blockIdx.x * blockDim.x + threadIdx.x;
  if (i < n) p[i] = 0;
}

__global__ void degree_hist_kernel(const int* __restrict__ col, int* __restrict__ deg, int E) {
  int i = blockIdx.x * blockDim.x + threadIdx.x;
  if (i < E) atomicAdd(&deg[col[i]], 1);
}

// 256 threads/block, 1024 elements/block: per-block sum of deg.
__global__ __launch_bounds__(256) void scan_blocksum_kernel(const int* __restrict__ deg,
                                                            int* __restrict__ bsum, int n) {
  __shared__ int ws[4];
  int base = blockIdx.x * 1024;
  int tid = threadIdx.x;
  int s = 0;
#pragma unroll
  for (int j = 0; j < 4; ++j) {
    int i = base + tid + j * 256;
    if (i < n) s += deg[i];
  }
#pragma unroll
  for (int d = 1; d < 64; d <<= 1) s += __shfl_xor(s, d, 64);
  if ((tid & 63) == 0) ws[tid >> 6] = s;
  __syncthreads();
  if (tid == 0) bsum[blockIdx.x] = ws[0] + ws[1] + ws[2] + ws[3];
}

// One wave: exclusive scan of nb (<=64) block sums in place; write total.
__global__ __launch_bounds__(64) void scan_bsum_kernel(int* __restrict__ bsum, int nb,
                                                       int* __restrict__ total) {
  int lane = threadIdx.x;
  int v = (lane < nb) ? bsum[lane] : 0;
  int incl = v;
#pragma unroll
  for (int d = 1; d < 64; d <<= 1) {
    int t = __shfl_up(incl, d, 64);
    if (lane >= d) incl += t;
  }
  if (lane < nb) bsum[lane] = incl - v;
  if (lane == 63) *total = incl;
}

// Per-block exclusive scan (1024 elems, 4/thread contiguous) + block offset;
// writes offs and dinv.
__global__ __launch_bounds__(256) void scan_final_kernel(const int* __restrict__ deg,
                                                         const int* __restrict__ bsum,
                                                         int* __restrict__ offs,
                                                         float* __restrict__ dinv, int n) {
  __shared__ int wsum[4];
  int tid = threadIdx.x;
  int lane = tid & 63;
  int wid = tid >> 6;
  int idx0 = blockIdx.x * 1024 + tid * 4;
  int v[4];
#pragma unroll
  for (int j = 0; j < 4; ++j) {
    int i = idx0 + j;
    v[j] = (i < n) ? deg[i] : 0;
  }
  int tsum = v[0] + v[1] + v[2] + v[3];
  int incl = tsum;
#pragma unroll
  for (int d = 1; d < 64; d <<= 1) {
    int t = __shfl_up(incl, d, 64);
    if (lane >= d) incl += t;
  }
  if (lane == 63) wsum[wid] = incl;
  __syncthreads();
  int woff = 0;
#pragma unroll
  for (int w = 0; w < 4; ++w)
    if (w < wid) woff += wsum[w];
  int run = woff + incl - tsum + bsum[blockIdx.x];
#pragma unroll
  for (int j = 0; j < 4; ++j) {
    int i = idx0 + j;
    if (i < n) {
      offs[i] = run;
      dinv[i] = rsqrtf((float)v[j] + 1.0f);
      run += v[j];
    }
  }
}

// bcur[b] = offs[b*256]; offs[N] = total.
__global__ void bucket_init_kernel(const int* __restrict__ offs, const int* __restrict__ total,
                                   int* __restrict__ bcur, int* __restrict__ offs_n, int NBK) {
  int b = blockIdx.x * blockDim.x + threadIdx.x;
  if (b < NBK) bcur[b] = offs[b * 256];
  if (b == 0) *offs_n = *total;
}

// binA: 4096 edges/block. LDS hist over <=256 buckets -> one global
// atomicAdd per (block,bucket) -> LDS-cursor scatter of packed (col<<16|row).
__global__ __launch_bounds__(256) void binA_kernel(const int* __restrict__ row,
                                                   const int* __restrict__ col,
                                                   int* __restrict__ bcur,
                                                   unsigned int* __restrict__ staging, int E,
                                                   int NBK) {
  __shared__ int hist[256];
  const int tid = threadIdx.x;
  hist[tid] = 0;
  __syncthreads();
  const int base = blockIdx.x * 4096;
  unsigned int payload[16];
  int bk[16];
#pragma unroll
  for (int j = 0; j < 16; ++j) {
    int i = base + j * 256 + tid;
    if (i < E) {
      unsigned int c = (unsigned int)col[i];
      unsigned int r = (unsigned int)row[i];
      payload[j] = (c << 16) | r;
      bk[j] = (int)(c >> 8);
      atomicAdd(&hist[bk[j]], 1);
    } else {
      bk[j] = -1;
    }
  }
  __syncthreads();
  if (tid < NBK) {
    int h = hist[tid];
    hist[tid] = h ? atomicAdd(&bcur[tid], h) : 0;
  }
  __syncthreads();
#pragma unroll
  for (int j = 0; j < 16; ++j) {
    if (bk[j] >= 0) {
      int p = atomicAdd(&hist[bk[j]], 1);
      staging[p] = payload[j];
    }
  }
}

// binB: one block per 256-node bucket; per-node LDS cursors; writes CSR
// entry = bf16(dinv[row])<<16 | row.
__global__ __launch_bounds__(512) void binB_kernel(const unsigned int* __restrict__ staging,
                                                   const int* __restrict__ offs,
                                                   const float* __restrict__ dinv,
                                                   unsigned int* __restrict__ csr, int N) {
  __shared__ int cur[256];
  const int b = blockIdx.x;
  const int n0 = b * 256;
  const int nn = min(256, N - n0);
  const int tid = threadIdx.x;
  if (tid < nn) cur[tid] = offs[n0 + tid];
  __syncthreads();
  const int s = offs[n0];
  const int e = offs[min(n0 + 256, N)];
  for (int t = s + tid; t < e; t += 512) {
    unsigned int v = staging[t];
    int cl = (int)((v >> 16) & 255u);
    unsigned int r = v & 0xFFFFu;
    unsigned int wd = f2bf(dinv[r]);
    int p = atomicAdd(&cur[cl], 1);
    csr[p] = (wd << 16) | r;
  }
}

// --------------------- weight prep: fragment ordering ----------------------
__global__ void prep_bfrag_kernel(const float* __restrict__ W, unsigned short* __restrict__ out,
                                  int K, int N) {
  int idx = blockIdx.x * blockDim.x + threadIdx.x;
  int KS = K / 32;
  int total = (N / 16) * KS * 64;
  if (idx >= total) return;
  int lane = idx & 63;
  int t = idx >> 6;
  int ks = t % KS;
  int nt = t / KS;
  int n = nt * 16 + (lane & 15);
  int k0 = ks * 32 + (lane >> 4) * 8;
  unsigned short* o = out + (size_t)idx * 8;
#pragma unroll
  for (int j = 0; j < 8; ++j) o[j] = f2bf(W[(size_t)(k0 + j) * N + n]);
}

// ------------------------------- MFMA GEMM ---------------------------------
template <int K, int N, bool ABF16>
__global__ __launch_bounds__(256) void mfma_gemm_kernel(const void* __restrict__ Ap,
                                                        const unsigned short* __restrict__ Bfrag,
                                                        unsigned short* __restrict__ Cout, int M) {
  constexpr int KS = K / 32;
  constexpr int NT = N / 16;
  const int lane = threadIdx.x & 63;
  const int wid = threadIdx.x >> 6;
  const int quad = lane >> 4;
  const int lc = lane & 15;
  const int mbase = blockIdx.x * 128 + wid * 32;
  if (mbase >= M) return;

  f32x4 acc[2][NT];
#pragma unroll
  for (int mt = 0; mt < 2; ++mt)
#pragma unroll
    for (int nt = 0; nt < NT; ++nt) acc[mt][nt] = (f32x4){0.f, 0.f, 0.f, 0.f};

  int r0 = mbase + lc;
  int r1 = mbase + 16 + lc;
  if (r0 >= M) r0 = M - 1;
  if (r1 >= M) r1 = M - 1;

#pragma unroll
  for (int ks = 0; ks < KS; ++ks) {
    const int k0 = ks * 32 + quad * 8;
    short8x a[2];
    if constexpr (ABF16) {
      const unsigned short* A = (const unsigned short*)Ap;
      a[0] = *(const short8x*)(A + (size_t)r0 * K + k0);
      a[1] = *(const short8x*)(A + (size_t)r1 * K + k0);
    } else {
      const float* A = (const float*)Ap;
      const float4* p0 = (const float4*)(A + (size_t)r0 * K + k0);
      const float4* p1 = (const float4*)(A + (size_t)r1 * K + k0);
      float4 u0 = p0[0], v0 = p0[1];
      float4 u1 = p1[0], v1 = p1[1];
      short8x t0, t1;
      t0[0] = (short)f2bf(u0.x); t0[1] = (short)f2bf(u0.y);
      t0[2] = (short)f2bf(u0.z); t0[3] = (short)f2bf(u0.w);
      t0[4] = (short)f2bf(v0.x); t0[5] = (short)f2bf(v0.y);
      t0[6] = (short)f2bf(v0.z); t0[7] = (short)f2bf(v0.w);
      t1[0] = (short)f2bf(u1.x); t1[1] = (short)f2bf(u1.y);
      t1[2] = (short)f2bf(u1.z); t1[3] = (short)f2bf(u1.w);
      t1[4] = (short)f2bf(v1.x); t1[5] = (short)f2bf(v1.y);
      t1[6] = (short)f2bf(v1.z); t1[7] = (short)f2bf(v1.w);
      a[0] = t0;
      a[1] = t1;
    }
#pragma unroll
    for (int nt = 0; nt < NT; ++nt) {
      short8x b = *(const short8x*)(Bfrag + (((size_t)nt * KS + ks) * 64 + lane) * 8);
      acc[0][nt] = __builtin_amdgcn_mfma_f32_16x16x32_bf16(a[0], b, acc[0][nt], 0, 0, 0);
      acc[1][nt] = __builtin_amdgcn_mfma_f32_16x16x32_bf16(a[1], b, acc[1][nt], 0, 0, 0);
    }
  }

#pragma unroll
  for (int mt = 0; mt < 2; ++mt)
#pragma unroll
    for (int nt = 0; nt < NT; ++nt)
#pragma unroll
      for (int reg = 0; reg < 4; ++reg) {
        int row = mbase + mt * 16 + quad * 4 + reg;
        if (row < M) Cout[(size_t)row * N + nt * 16 + lc] = f2bf(acc[mt][nt][reg]);
      }
}

// --------------------------- aggregation (bf16) ----------------------------
// CSR entry packs bf16 edge weight (dinv[row]) in high 16 bits, row in low.
template <int F>
__global__ void agg_bn_relu_kernel(const unsigned short* __restrict__ xw,
                                   const int* __restrict__ offs,
                                   const unsigned int* __restrict__ csr,
                                   const float* __restrict__ dinv, const float* __restrict__ bias,
                                   const float* __restrict__ gamma, const float* __restrict__ beta,
                                   const float* __restrict__ mean, const float* __restrict__ var,
                                   unsigned short* __restrict__ out) {
  const int i = blockIdx.x;
  const int f = threadIdx.x;
  const float di = dinv[i];
  const int s = offs[i], e = offs[i + 1];
  float acc = 0.f;
  int t = s;
  for (; t + 4 <= e; t += 4) {
    unsigned int e0 = csr[t], e1 = csr[t + 1], e2 = csr[t + 2], e3 = csr[t + 3];
    acc += bf2f(e0 >> 16) * bf2f(xw[(size_t)(e0 & 0xFFFFu) * F + f]) +
           bf2f(e1 >> 16) * bf2f(xw[(size_t)(e1 & 0xFFFFu) * F + f]) +
           bf2f(e2 >> 16) * bf2f(xw[(size_t)(e2 & 0xFFFFu) * F + f]) +
           bf2f(e3 >> 16) * bf2f(xw[(size_t)(e3 & 0xFFFFu) * F + f]);
  }
  for (; t < e; ++t) {
    unsigned int e0 = csr[t];
    acc += bf2f(e0 >> 16) * bf2f(xw[(size_t)(e0 & 0xFFFFu) * F + f]);
  }
  float v = di * acc + di * di * bf2f(xw[(size_t)i * F + f]) + bias[f];
  v = (v - mean[f]) * rsqrtf(var[f] + 1e-5f) * gamma[f] + beta[f];
  out[(size_t)i * F + f] = f2bf(fmaxf(v, 0.f));
}

// ------------------------------- edge head ---------------------------------
__global__ __launch_bounds__(256) void head_mfma_kernel(
    const unsigned short* __restrict__ z, const int* __restrict__ src,
    const int* __restrict__ dst, const unsigned short* __restrict__ bfragH,
    const float* __restrict__ hb1, const float* __restrict__ hw2,
    const float* __restrict__ hb2, float* __restrict__ out, int P) {
  const int lane = threadIdx.x & 63;
  const int quad = lane >> 4;
  const int lc = lane & 15;

  short8x bf[4][4];
#pragma unroll
  for (int nt = 0; nt < 4; ++nt)
#pragma unroll
    for (int ks = 0; ks < 4; ++ks)
      bf[nt][ks] = *(const short8x*)(bfragH + (((size_t)nt * 4 + ks) * 64 + lane) * 8);

  float b1v[4], w2v[4];
#pragma unroll
  for (int nt = 0; nt < 4; ++nt) {
    b1v[nt] = hb1[nt * 16 + lc];
    w2v[nt] = hw2[nt * 16 + lc];
  }
  const float bias2 = hb2[0];

  const int nchunks = (P + 15) / 16;
  const int gw = blockIdx.x * 4 + (threadIdx.x >> 6);
  const int nw = gridDim.x * 4;

  for (int ch = gw; ch < nchunks; ch += nw) {
    int p = ch * 16 + lc;
    int pc = p < P ? p : P - 1;
    int s = src[pc], d = dst[pc];
    const unsigned short* zs = z + (size_t)s * 64;
    const unsigned short* zd = z + (size_t)d * 64;
    short8x a[4];
    a[0] = *(const short8x*)(zs + quad * 8);
    a[1] = *(const short8x*)(zs + 32 + quad * 8);
    a[2] = *(const short8x*)(zd + quad * 8);
    a[3] = *(const short8x*)(zd + 32 + quad * 8);

    f32x4 acc[4];
#pragma unroll
    for (int nt = 0; nt < 4; ++nt) acc[nt] = (f32x4){0.f, 0.f, 0.f, 0.f};
#pragma unroll
    for (int nt = 0; nt < 4; ++nt)
#pragma unroll
      for (int t = 0; t < 4; ++t)
        acc[nt] = __builtin_amdgcn_mfma_f32_16x16x32_bf16(a[t], bf[nt][t], acc[nt], 0, 0, 0);

    float part[4];
#pragma unroll
    for (int reg = 0; reg < 4; ++reg) {
      float sum = 0.f;
#pragma unroll
      for (int nt = 0; nt < 4; ++nt) sum += fmaxf(acc[nt][reg] + b1v[nt], 0.f) * w2v[nt];
      part[reg] = sum;
    }
#pragma unroll
    for (int m = 1; m < 16; m <<= 1) {
#pragma unroll
      for (int reg = 0; reg < 4; ++reg) part[reg] += __shfl_xor(part[reg], m, 64);
    }
    if (lc == 0) {
      int pbase = ch * 16 + quad * 4;
      float4 o;
      o.x = 1.0f / (1.0f + __expf(-(part[0] + bias2)));
      o.y = 1.0f / (1.0f + __expf(-(part[1] + bias2)));
      o.z = 1.0f / (1.0f + __expf(-(part[2] + bias2)));
      o.w = 1.0f / (1.0f + __expf(-(part[3] + bias2)));
      if (pbase + 3 < P) {
        *(float4*)(out + pbase) = o;
      } else {
        float ov[4] = {o.x, o.y, o.z, o.w};
        for (int reg = 0; reg < 4; ++reg)
          if (pbase + reg < P) out[pbase + reg] = ov[reg];
      }
    }
  }
}

// ------------------------------- launcher ----------------------------------

extern "C" void kernel_launch(void* const* d_in, const int* in_sizes, int n_in,
                              void* d_out, int out_size, void* d_ws, size_t ws_size,
                              hipStream_t stream) {
  const float* x = (const float*)d_in[0];
  const int* ei = (const int*)d_in[1];
  const int* src = (const int*)d_in[2];
  const int* dst = (const int*)d_in[3];
  const float* W1 = (const float*)d_in[4];
  const float* b1 = (const float*)d_in[5];
  const float* g1 = (const float*)d_in[6];
  const float* be1 = (const float*)d_in[7];
  const float* mu1 = (const float*)d_in[8];
  const float* va1 = (const float*)d_in[9];
  const float* W2 = (const float*)d_in[10];
  const float* b2 = (const float*)d_in[11];
  const float* g2 = (const float*)d_in[12];
  const float* be2 = (const float*)d_in[13];
  const float* mu2 = (const float*)d_in[14];
  const float* va2 = (const float*)d_in[15];
  const float* hW1 = (const float*)d_in[16];
  const float* hb1 = (const float*)d_in[17];
  const float* hW2 = (const float*)d_in[18];
  const float* hb2 = (const float*)d_in[19];
  float* out = (float*)d_out;

  const int N = in_sizes[0] / 512;
  const int E = in_sizes[1] / 2;
  const int P = in_sizes[2];
  const int* row = ei;
  const int* col = ei + E;
  const int NBK = (N + 255) / 256;    // scatter buckets (256 nodes each)
  const int NSB = (N + 1023) / 1024;  // scan blocks
  const int NAB = (E + 4095) / 4096;  // binA blocks

  char* wp = (char*)d_ws;
  auto alloc = [&](size_t bytes) {
    char* p = wp;
    wp += (bytes + 255) & ~(size_t)255;
    return p;
  };
  unsigned short* xw1 = (unsigned short*)alloc((size_t)N * 128 * 2);
  unsigned short* h = (unsigned short*)alloc((size_t)N * 128 * 2);
  unsigned short* xw2 = (unsigned short*)alloc((size_t)N * 64 * 2);
  unsigned short* z = (unsigned short*)alloc((size_t)N * 64 * 2);
  float* dinv = (float*)alloc((size_t)N * 4);
  int* deg = (int*)alloc((size_t)N * 4);
  int* offs = (int*)alloc((size_t)(N + 1) * 4);
  unsigned int* csr = (unsigned int*)alloc((size_t)E * 4);
  unsigned int* staging = (unsigned int*)alloc((size_t)E * 4);
  int* bsum = (int*)alloc((size_t)NSB * 4);
  int* bcur = (int*)alloc((size_t)NBK * 4);
  int* total = (int*)alloc(256);
  unsigned short* bfW1 = (unsigned short*)alloc(512 * 128 * 2);
  unsigned short* bfW2 = (unsigned short*)alloc(128 * 64 * 2);
  unsigned short* bfH = (unsigned short*)alloc(128 * 64 * 2);
  (void)ws_size;
  (void)n_in;
  (void)out_size;

  // --- graph structure ---
  hipLaunchKernelGGL(zero_int_kernel, dim3((N + 255) / 256), dim3(256), 0, stream, deg, N);
  hipLaunchKernelGGL(degree_hist_kernel, dim3((E + 255) / 256), dim3(256), 0, stream, col, deg, E);
  hipLaunchKernelGGL(scan_blocksum_kernel, dim3(NSB), dim3(256), 0, stream, deg, bsum, N);
  hipLaunchKernelGGL(scan_bsum_kernel, dim3(1), dim3(64), 0, stream, bsum, NSB, total);
  hipLaunchKernelGGL(scan_final_kernel, dim3(NSB), dim3(256), 0, stream, deg, bsum, offs, dinv, N);
  hipLaunchKernelGGL(bucket_init_kernel, dim3((NBK + 255) / 256), dim3(256), 0, stream, offs, total,
                     bcur, offs + N, NBK);
  hipLaunchKernelGGL(binA_kernel, dim3(NAB), dim3(256), 0, stream, row, col, bcur, staging, E, NBK);
  hipLaunchKernelGGL(binB_kernel, dim3(NBK), dim3(512), 0, stream, staging, offs, dinv, csr, N);

  // --- weight fragment prep ---
  hipLaunchKernelGGL(prep_bfrag_kernel, dim3((8 * 16 * 64 + 255) / 256), dim3(256), 0, stream, W1,
                     bfW1, 512, 128);
  hipLaunchKernelGGL(prep_bfrag_kernel, dim3((4 * 4 * 64 + 255) / 256), dim3(256), 0, stream, W2,
                     bfW2, 128, 64);
  hipLaunchKernelGGL(prep_bfrag_kernel, dim3((4 * 4 * 64 + 255) / 256), dim3(256), 0, stream, hW1,
                     bfH, 128, 64);

  // --- layer 1 ---
  hipLaunchKernelGGL((mfma_gemm_kernel<512, 128, false>), dim3((N + 127) / 128), dim3(256), 0,
                     stream, x, bfW1, xw1, N);
  hipLaunchKernelGGL((agg_bn_relu_kernel<128>), dim3(N), dim3(128), 0, stream, xw1, offs, csr,
                     dinv, b1, g1, be1, mu1, va1, h);

  // --- layer 2 ---
  hipLaunchKernelGGL((mfma_gemm_kernel<128, 64, true>), dim3((N + 127) / 128), dim3(256), 0, stream,
                     h, bfW2, xw2, N);
  hipLaunchKernelGGL((agg_bn_relu_kernel<64>), dim3(N), dim3(64), 0, stream, xw2, offs, csr, dinv,
                     b2, g2, be2, mu2, va2, z);

  // --- edge head ---
  hipLaunchKernelGGL(head_mfma_kernel, dim3(2048), dim3(256), 0, stream, z, src, dst, bfH, hb1,
                     hW2, hb2, out, P);
}